// Round 8
// baseline (363.027 us; speedup 1.0000x reference)
//
#include <hip/hip_runtime.h>
#include <hip/hip_bf16.h>

// Problem: B=4, L=4096, DH=1024, T=1024, DG=768, P=256
// Inputs fp32 + bool mask (width auto-detect); OUTPUT fp32.
//
// MASK COMPACTION: ~50% of l are masked; masked columns have alpha == 0
// exactly. All passes work in compact index space (K/S/Z do ~half work).
//
// 4-DISPATCH PIPELINE (round 8; was 6 — each removed dispatch ~3.3us):
//   1) prep_all: h-gather blocks recompute the valid-l scan IN-BLOCK from
//      the L2-resident 16KB mask (no scan kernel, no global idx buffer);
//      + cvt Wk/Wq/G; + rowsum zeroing blocks.
//   2) qk_gemm:  Q = Gbf@Wq^T and K_c = Hbf_c@Wk^T (K-part popcounts its
//      batch's mask for the row-tile early-exit).
//   3) s_gemm:   P_c = exp(Q@K_c^T/16), cols >= Lc zeroed by compare;
//      fp32 rowsum atomics. (popcount-derived Lc/Lc_pad.)
//   4) z_gemm:   Z = (P_c @ Ht_c^T) * (1/rowsum), M-SPLIT 64x128 tiles,
//      grid (16,8,4)=512 WGs (2 blocks/CU like the old split-K2), FULL K
//      per WG -> normalized direct fp32 store. NO combine kernel, NO
//      partial buffers (round-7 had 33.6MB write + 33.6MB re-read).
//
// GEMM K-loop: COUNTED-VMCNT pipeline (T4), 3 LDS buffers, prefetch depth 2;
// GRANULE-XOR LDS swizzle (conflicts == 0, verified); bf16 epilogues via
// LDS-staged 16B/lane vectorized writeout; XCD-chunked blockIdx swizzle (T1).
// Body templated on BM (64 or 128): BM=64 waves cover 32x64, 3 gloads/tile
// (vmcnt(3)); BM=128 unchanged (vmcnt(4)).

typedef __attribute__((ext_vector_type(8))) short short8;   // 8 bf16 = 4 VGPRs
typedef __attribute__((ext_vector_type(4))) float f32x4;

static __device__ __forceinline__ unsigned short bf16bits(float x) {
    __hip_bfloat16 b = __float2bfloat16(x);
    return *(unsigned short*)&b;
}

// Async global->LDS, 16 B per lane. LDS dest = wave-uniform base + lane*16.
static __device__ __forceinline__ void gload_lds16(const __hip_bfloat16* g,
                                                   __hip_bfloat16* l)
{
    auto gp = (const __attribute__((address_space(1))) unsigned int*)(uintptr_t)g;
    auto lp = (__attribute__((address_space(3))) unsigned int*)(unsigned int)(uintptr_t)l;
    __builtin_amdgcn_global_load_lds(gp, lp, 16, 0, 0);
}

// ---------------------------------------------------------------------------
// Mask helpers: every consumer recomputes width/counts from the 16KB
// L2-resident mask (cheaper than a dedicated dispatch + gap).
// sh: >= 6 ints of shared scratch. All return wave-uniform values.
// ---------------------------------------------------------------------------
static __device__ bool masked_at(const void* mask, int w, long i)
{
    if (w == 1) return ((const unsigned char*)mask)[i] != 0;
    if (w == 2) return ((const unsigned short*)mask)[i] != 0;
    if (w == 4) return ((const unsigned int*)mask)[i] != 0;
    uint2 q = ((const uint2*)mask)[i]; return (q.x | q.y) != 0;
}

static __device__ int detect_width_dev(const void* mask, int* sh)
{
    const int tid = threadIdx.x;
    const unsigned char*  m8  = (const unsigned char*)mask;
    const unsigned short* m16 = (const unsigned short*)mask;
    const unsigned int*   m32 = (const unsigned int*)mask;
    if (tid < 5) sh[tid] = 0;
    __syncthreads();
    int l1 = 0, l2 = 0, l4 = 0, l8 = 0, lp = 0;
    for (int i = tid; i < 16384; i += 256) l1 += (m8[i] != 0);
    for (int i = tid; i < 8192;  i += 256) {
        l2 += (m16[i] != 0);
        lp += ((m8[2 * i] != 0) == (m8[2 * i + 1] != 0));
    }
    for (int i = tid; i < 4096;  i += 256) l4 += (m32[i] != 0);
    for (int i = tid; i < 2048;  i += 256) l8 += ((m32[2 * i] | m32[2 * i + 1]) != 0);
    atomicAdd(&sh[0], l1); atomicAdd(&sh[1], l2); atomicAdd(&sh[2], l4);
    atomicAdd(&sh[3], l8); atomicAdd(&sh[4], lp);
    __syncthreads();
    const float f1 = fabsf(sh[0] / 16384.f - 0.5f);
    const float f2 = fabsf(sh[1] / 8192.f  - 0.5f);
    const float f4 = fabsf(sh[2] / 4096.f  - 0.5f);
    const float f8 = fabsf(sh[3] / 2048.f  - 0.5f);
    int w = 1; float best = f1;
    if (f2 < best) { best = f2; w = 2; }
    if (f4 < best) { best = f4; w = 4; }
    if (f8 < best) { best = f8; w = 8; }
    if (w == 1 && sh[4] > 7400) w = 2;
    return w;
}

// popcount of valid keys in batch b (deterministic across kernels)
static __device__ int count_valid_dev(const void* mask, int w, int b, int L, int* sh)
{
    const int tid = threadIdx.x;
    if (tid == 0) sh[5] = 0;
    __syncthreads();
    int cnt = 0;
    for (int i = tid; i < L; i += 256)
        cnt += masked_at(mask, w, (long)b * L + i) ? 0 : 1;
    #pragma unroll
    for (int off = 32; off; off >>= 1) cnt += __shfl_xor(cnt, off, 64);
    if ((tid & 63) == 0) atomicAdd(&sh[5], cnt);
    __syncthreads();
    return sh[5];
}

// ---------------------------------------------------------------------------
// Fused prep: blocks [0, 4096) = H gather/convert/transpose with IN-BLOCK
// valid-l scan; [4096, 7616) = cvt Wk/Wq/G; [7616, 7632) = rowsum zero.
// ---------------------------------------------------------------------------
__global__ __launch_bounds__(256)
void prep_all_kernel(const float* __restrict__ H,
                     __hip_bfloat16* __restrict__ Hbf,
                     __hip_bfloat16* __restrict__ Ht,
                     const void* __restrict__ mask,
                     const float* __restrict__ Wk, unsigned short* __restrict__ Wkbf,
                     const float* __restrict__ Wq, unsigned short* __restrict__ Wqbf,
                     const float* __restrict__ G,  unsigned short* __restrict__ Gbf,
                     float* __restrict__ rowsum,
                     int L, int D)
{
    __shared__ __align__(16) __hip_bfloat16 tile[64][72];  // [d][c], pad 8
    __shared__ unsigned short sidx[4096];
    __shared__ int sh[8];
    int id = blockIdx.x;
    const int tid = threadIdx.x;
    if (id < 4096) {
        // --- h gather: c-tile (id&63), d-tile ((id>>6)&15), b (id>>10) ---
        const int b  = id >> 10;
        const int c0 = (id & 63) * 64;
        const int d0 = ((id >> 6) & 15) * 64;

        // in-block valid-l scan for batch b (16 l's per thread)
        const int w = detect_width_dev(mask, sh);
        bool v[16];
        int cnt = 0;
        #pragma unroll
        for (int i = 0; i < 16; ++i) {
            const int l = tid * 16 + i;
            v[i] = !masked_at(mask, w, (long)b * L + l);
            cnt += v[i] ? 1 : 0;
        }
        int pre = cnt;
        #pragma unroll
        for (int off = 1; off < 64; off <<= 1) {
            const int t = __shfl_up(pre, off, 64);
            if ((tid & 63) >= off) pre += t;
        }
        __syncthreads();                  // sh[0..4] reads done; reuse as waveTot
        if ((tid & 63) == 63) sh[tid >> 6] = pre;
        __syncthreads();
        int waveOff = 0;
        for (int wv = 0; wv < (tid >> 6); ++wv) waveOff += sh[wv];
        int o = waveOff + pre - cnt;      // exclusive prefix
        #pragma unroll
        for (int i = 0; i < 16; ++i)
            if (v[i]) sidx[o++] = (unsigned short)(tid * 16 + i);
        if (tid == 255) sh[6] = waveOff + pre;
        __syncthreads();
        const int Lcb = sh[6];
        const int lcpadb = (Lcb + 127) & ~127;
        if (c0 >= lcpadb) return;         // beyond padded extent (block-uniform)

        const float* Hb = H + (long)b * L * D;
        __hip_bfloat16* Hbfb = Hbf + (long)b * L * D;
        __hip_bfloat16* Htb  = Ht  + (long)b * D * L;
        const int tx = tid & 15, ty = tid >> 4;  // 16 x 16
        #pragma unroll
        for (int p = 0; p < 4; ++p) {
            const int row = ty + p * 16;     // compact index within tile
            const int c = c0 + row;
            float4 vv = {0.f, 0.f, 0.f, 0.f};
            if (c < Lcb) {
                const int l = sidx[c];
                vv = *(const float4*)(&Hb[(long)l * D + d0 + tx * 4]);
            }
            ushort4 oo;
            oo.x = bf16bits(vv.x); oo.y = bf16bits(vv.y);
            oo.z = bf16bits(vv.z); oo.w = bf16bits(vv.w);
            *(ushort4*)(&Hbfb[(long)c * D + d0 + tx * 4]) = oo;
            tile[tx * 4 + 0][row] = __float2bfloat16(vv.x);
            tile[tx * 4 + 1][row] = __float2bfloat16(vv.y);
            tile[tx * 4 + 2][row] = __float2bfloat16(vv.z);
            tile[tx * 4 + 3][row] = __float2bfloat16(vv.w);
        }
        __syncthreads();
        const int ll = tid & 7;      // 8 threads x 16B = 128B per d-row
        const int dq = tid >> 3;     // 32 d-rows per pass
        #pragma unroll
        for (int q = 0; q < 2; ++q) {
            const int dd = dq + q * 32;
            const short8 vv = *(const short8*)(&tile[dd][ll * 8]);
            *(short8*)(&Htb[(long)(d0 + dd) * L + c0 + ll * 8]) = vv;
        }
        return;
    }
    id -= 4096;
    if (id >= 3520) {                    // rowsum zero: 16 blocks x 256
        rowsum[(id - 3520) * 256 + tid] = 0.f;
        return;
    }
    // --- cvt ranges ---
    const float* in; unsigned short* out; int n4;
    if (id < 256)       { in = Wk; out = Wkbf; n4 = (256 * 1024) / 4; }
    else if (id < 448)  { id -= 256; in = Wq; out = Wqbf; n4 = (256 * 768) / 4; }
    else                { id -= 448; in = G;  out = Gbf;  n4 = (4 * 1024 * 768) / 4; }
    const int i = id * 256 + tid;
    if (i >= n4) return;
    float4 v = ((const float4*)in)[i];
    ushort4 o;
    o.x = bf16bits(v.x); o.y = bf16bits(v.y);
    o.z = bf16bits(v.z); o.w = bf16bits(v.w);
    ((ushort4*)out)[i] = o;
}

// ---------------------------------------------------------------------------
// GEMM body: C[M,N] (op)= scale * A[M,K] @ Bm[N,K]^T  (bf16 row-major)
// Tile BM x 128, 4 waves. BM=128: wave 64x64, 4x4 frags, 4 gloads/tile.
// BM=64: wave 32x64, 2x4 frags, 3 gloads/tile. Counted-vmcnt 3-buffer
// pipeline; lds_pool (48 KiB) reused for the bf16 epilogue.
// MODE 0: plain store (bf16 via LDS writeout / fp32 direct).
// MODE 2: P = exp(scale*acc); cols >= lcv -> 0; bf16 writeout; rowsum atomics.
// MODE 3: fp32 direct store * (1/rowsum[row])  (fused softmax normalize).
// ---------------------------------------------------------------------------
template <typename OutT, int MODE, int BM>
static __device__ __forceinline__
void gemm_bt_body(int bx, int by, int zb, __hip_bfloat16* lds_pool,
                  const __hip_bfloat16* __restrict__ A,
                  const __hip_bfloat16* __restrict__ Bm,
                  OutT* __restrict__ C,
                  int K, int lda, int ldb, int ldc,
                  long batchStrideA, long batchStrideB, long batchStrideC,
                  float scale,
                  float* __restrict__ rowsum, int rowsumStride, int lcv)
{
    constexpr int MI  = BM / 32;        // frag rows per wave
    constexpr int ACH = BM / 64;        // A staging chunks per wave
    constexpr int ATS = BM * 32;        // A tile elems per buffer

    A  += (long)zb * batchStrideA;
    Bm += (long)zb * batchStrideB;
    C  += (long)zb * batchStrideC;
    const int NT = K / 32;              // k-tiles (>= 4 always here)

    const int tid  = threadIdx.x;
    const int lane = tid & 63;
    const int wave = tid >> 6;
    const int wm = (wave & 1) * (BM / 2);
    const int wn = (wave >> 1) * 64;
    const int rowBase = bx * BM;
    const int colBase = by * 128;

    __hip_bfloat16* AsP = lds_pool;            // buf*ATS + row*32 + col
    __hip_bfloat16* BsP = lds_pool + 3 * ATS;

    f32x4 acc[MI][4];
    #pragma unroll
    for (int i = 0; i < MI; ++i)
        #pragma unroll
        for (int j = 0; j < 4; ++j)
            acc[i][j] = (f32x4){0.f, 0.f, 0.f, 0.f};

    // Staging: wave w covers BM/4 A-rows + 32 B-rows as 16-row x 1024 B chunks.
    // Lane i: LDS lands at (row = i>>2, granule g = i&3). Pre-swizzle the
    // GLOBAL source granule: q = g ^ ((row>>1)&3)  (involution per row).
    const int srow = lane >> 2;
    const int scol = ((lane & 3) ^ ((lane >> 3) & 3)) * 8;   // swizzled source col
    const long ar0 = (long)(rowBase + wave * (BM / 4) + srow) * lda;
    const long ar1 = ar0 + 16l * lda;                         // ACH==2 only
    const long br0 = (long)(colBase + wave * 32 + srow) * ldb;
    const long br1 = br0 + 16l * ldb;

    const int mrow = lane & 15;         // fragment m/n index
    // Swizzled fragment k-offset (row bases ≡0 mod 16 -> lane-only term).
    const int koff = (((lane >> 4) ^ ((lane >> 1) & 3)) * 8);

    // Per wave each tile issues EXACTLY ACH+2 global_load_lds ops.
    auto stage = [&](int buf, int t) {
        const int kk = t * 32 + scol;
        gload_lds16(A + ar0 + kk, AsP + buf * ATS + wave * (BM / 4) * 32);
        if constexpr (ACH == 2)
            gload_lds16(A + ar1 + kk, AsP + buf * ATS + wave * (BM / 4) * 32 + 512);
        gload_lds16(Bm + br0 + kk, BsP + buf * 4096 + wave * 1024);
        gload_lds16(Bm + br1 + kk, BsP + buf * 4096 + wave * 1024 + 512);
    };

    // Prologue: tiles 0,1 in flight. No barrier yet.
    stage(0, 0);
    stage(1, 1);

    int cur = 0;
    for (int t = 0; t < NT; ++t) {
        // Drain OWN tile-t loads only; tile t+1 stays in flight across the
        // barrier (counted vmcnt — never drain to 0 in the main loop).
        if (t + 1 < NT) {
            if constexpr (ACH == 2)
                asm volatile("s_waitcnt vmcnt(4)" ::: "memory");
            else
                asm volatile("s_waitcnt vmcnt(3)" ::: "memory");
        } else {
            asm volatile("s_waitcnt vmcnt(0)" ::: "memory");
        }
        __builtin_amdgcn_s_barrier();
        if (t + 2 < NT) {
            const int nxt2 = (cur >= 1) ? cur - 1 : cur + 2;   // (cur+2)%3
            stage(nxt2, t + 2);
        }

        short8 af[MI], bf[4];
        #pragma unroll
        for (int mi = 0; mi < MI; ++mi)
            af[mi] = *(const short8*)(AsP + cur * ATS + (wm + mi * 16 + mrow) * 32 + koff);
        #pragma unroll
        for (int ni = 0; ni < 4; ++ni)
            bf[ni] = *(const short8*)(BsP + cur * 4096 + (wn + ni * 16 + mrow) * 32 + koff);

        #pragma unroll
        for (int mi = 0; mi < MI; ++mi)
            #pragma unroll
            for (int ni = 0; ni < 4; ++ni)
                acc[mi][ni] = __builtin_amdgcn_mfma_f32_16x16x32_bf16(
                    af[mi], bf[ni], acc[mi][ni], 0, 0, 0);
        cur = (cur == 2) ? 0 : cur + 1;
    }

    // C/D layout (verified m89/m91): col = lane&15, row = (lane>>4)*4 + r
    const int crow0 = (lane >> 4) * 4;
    const int ccol  = lane & 15;

    if constexpr (MODE == 2) {
        // --- exp + compare-mask + rowsum; bf16 LDS-staged writeout ---
        __syncthreads();                   // pool safe: vmcnt(0) drained above
        __hip_bfloat16* cst = lds_pool;    // [128][136], granule^(row>>3)
        bool mk[4];
        #pragma unroll
        for (int ni = 0; ni < 4; ++ni)
            mk[ni] = (colBase + wn + ni * 16 + ccol) >= lcv;
        #pragma unroll
        for (int mi = 0; mi < MI; ++mi) {
            #pragma unroll
            for (int r = 0; r < 4; ++r) {
                const int row = wm + mi * 16 + crow0 + r;
                float rs = 0.f;
                #pragma unroll
                for (int ni = 0; ni < 4; ++ni) {
                    const int col = wn + ni * 16 + ccol;
                    const float e = mk[ni] ? 0.f
                                           : __expf(acc[mi][ni][r] * scale);
                    const __hip_bfloat16 pb = __float2bfloat16(e);
                    cst[row * 136 + (((col >> 3) ^ (row >> 3)) << 3) + (col & 7)] = pb;
                    rs += __bfloat162float(pb);
                }
                rs += __shfl_xor(rs, 1, 64);
                rs += __shfl_xor(rs, 2, 64);
                rs += __shfl_xor(rs, 4, 64);
                rs += __shfl_xor(rs, 8, 64);
                if ((lane & 15) == 0)
                    atomicAdd(&rowsum[(long)zb * rowsumStride + rowBase + row], rs);
            }
        }
        __syncthreads();
        const int g   = tid & 15;
        const int r4  = tid >> 4;
        const int lof = ((g ^ r4) << 3);
        #pragma unroll
        for (int k = 0; k < 8; ++k) {
            const int row = r4 * 8 + k;
            const short8 v = *(const short8*)(cst + row * 136 + lof);
            *(short8*)(&((__hip_bfloat16*)C)[(long)(rowBase + row) * ldc + colBase + g * 8]) = v;
        }
    } else if constexpr (MODE == 3) {
        // fp32 direct store with fused 1/rowsum normalize (Z output)
        #pragma unroll
        for (int mi = 0; mi < MI; ++mi) {
            #pragma unroll
            for (int r = 0; r < 4; ++r) {
                const int row = rowBase + wm + mi * 16 + crow0 + r;
                const float inv = 1.0f / rowsum[(long)zb * rowsumStride + row];
                #pragma unroll
                for (int ni = 0; ni < 4; ++ni) {
                    const int col = colBase + wn + ni * 16 + ccol;
                    ((float*)C)[(long)row * ldc + col] = acc[mi][ni][r] * inv;
                }
            }
        }
    } else if constexpr (sizeof(OutT) == 2) {
        // bf16 LDS-staged writeout (Q/K outputs)
        __syncthreads();
        __hip_bfloat16* cst = lds_pool;
        #pragma unroll
        for (int mi = 0; mi < MI; ++mi) {
            #pragma unroll
            for (int ni = 0; ni < 4; ++ni) {
                #pragma unroll
                for (int r = 0; r < 4; ++r) {
                    const int row = wm + mi * 16 + crow0 + r;
                    const int col = wn + ni * 16 + ccol;
                    cst[row * 136 + (((col >> 3) ^ (row >> 3)) << 3) + (col & 7)] =
                        __float2bfloat16(acc[mi][ni][r] * scale);
                }
            }
        }
        __syncthreads();
        const int g   = tid & 15;
        const int r4  = tid >> 4;
        const int lof = ((g ^ r4) << 3);
        #pragma unroll
        for (int k = 0; k < 8; ++k) {
            const int row = r4 * 8 + k;
            const short8 v = *(const short8*)(cst + row * 136 + lof);
            *(short8*)(&((__hip_bfloat16*)C)[(long)(rowBase + row) * ldc + colBase + g * 8]) = v;
        }
    } else {
        // fp32 direct stores
        #pragma unroll
        for (int mi = 0; mi < MI; ++mi) {
            #pragma unroll
            for (int ni = 0; ni < 4; ++ni) {
                #pragma unroll
                for (int r = 0; r < 4; ++r) {
                    const int row = rowBase + wm + mi * 16 + crow0 + r;
                    const int col = colBase + wn + ni * 16 + ccol;
                    ((float*)C)[(long)row * ldc + col] = acc[mi][ni][r] * scale;
                }
            }
        }
    }
}

// XCD-chunked swizzle (T1): remap so each XCD owns a contiguous grid chunk.
static __device__ __forceinline__ void xcd_swizzle(int& bx, int& by, int& bz)
{
    const int nwg = gridDim.x * gridDim.y * gridDim.z;
    bx = blockIdx.x; by = blockIdx.y; bz = blockIdx.z;
    if ((nwg & 7) == 0) {
        int lin = bx + gridDim.x * (by + gridDim.y * bz);
        lin = (lin & 7) * (nwg >> 3) + (lin >> 3);
        bx = lin % gridDim.x;
        const int t = lin / gridDim.x;
        by = t % gridDim.y;
        bz = t / gridDim.y;
    }
}

// ---------------------------------------------------------------------------
// Merged Q-GEMM + K-GEMM launch. Grid (160, 2, 1):
//   bx <  32: Q = Gbf @ Wq^T   [B*T=4096 rows, K=DG=768]
//   bx >= 32: K = Hbf_c @ Wk^T [B*L row cap, K=DH=1024]; popcount row-exit
// ---------------------------------------------------------------------------
__global__ __launch_bounds__(256)
void qk_gemm_kernel(const __hip_bfloat16* __restrict__ Gbf,
                    const __hip_bfloat16* __restrict__ Wqbf,
                    __hip_bfloat16* __restrict__ Qbf,
                    const __hip_bfloat16* __restrict__ Hbf,
                    const __hip_bfloat16* __restrict__ Wkbf,
                    __hip_bfloat16* __restrict__ Kbf,
                    const void* __restrict__ mask,
                    int DG_, int DH_, int P_, int L_)
{
    __shared__ __align__(16) __hip_bfloat16 lds_pool[24576];
    int bx, by, bz;
    xcd_swizzle(bx, by, bz);
    if (bx < 32) {
        gemm_bt_body<__hip_bfloat16, 0, 128>(bx, by, 0, lds_pool,
            Gbf, Wqbf, Qbf, DG_, DG_, DG_, P_, 0, 0, 0, 1.0f,
            nullptr, 0, 0);
    } else {
        int* sh = (int*)lds_pool;
        const int w = detect_width_dev(mask, sh);
        const int rowBase = (bx - 32) * 128;
        const int bb = rowBase / L_;
        const int cnt = count_valid_dev(mask, w, bb, L_, sh);
        const int lcpadb = (cnt + 127) & ~127;
        __syncthreads();                 // sh reads done before pool reuse
        if (rowBase - bb * L_ >= lcpadb) return;
        gemm_bt_body<__hip_bfloat16, 0, 128>(bx - 32, by, 0, lds_pool,
            Hbf, Wkbf, Kbf, DH_, DH_, DH_, P_, 0, 0, 0, 1.0f,
            nullptr, 0, 0);
    }
}

// ---------------------------------------------------------------------------
// S-GEMM: P_c = exp(Q @ K_c^T * P^-0.5); cols >= Lc -> 0; rowsum atomics.
// ---------------------------------------------------------------------------
__global__ __launch_bounds__(256)
void s_gemm_kernel(const __hip_bfloat16* __restrict__ Qbf,
                   const __hip_bfloat16* __restrict__ Kbf,
                   __hip_bfloat16* __restrict__ Sb,
                   const void* __restrict__ mask,
                   float* __restrict__ rowsum,
                   int P_, int L_, int T_)
{
    __shared__ __align__(16) __hip_bfloat16 lds_pool[24576];
    int bx, by, bz;
    xcd_swizzle(bx, by, bz);
    int* sh = (int*)lds_pool;
    const int w = detect_width_dev(mask, sh);
    const int lcv = count_valid_dev(mask, w, bz, L_, sh);
    const int lcpadb = (lcv + 127) & ~127;
    __syncthreads();                     // sh reads done before pool reuse
    if (by * 128 >= lcpadb) return;      // masked-out col tile
    gemm_bt_body<__hip_bfloat16, 2, 128>(bx, by, bz, lds_pool,
        Qbf, Kbf, Sb, P_, P_, P_, L_,
        (long)T_ * P_, (long)L_ * P_, (long)T_ * L_, 0.0625f,
        rowsum, T_, lcv);
}

// ---------------------------------------------------------------------------
// Z-GEMM: Z = (P_c @ Ht_c^T) * (1/rowsum). 64x128 tiles (M-split, full K
// per WG -> no combine pass), runtime K = Lc_pad from popcount.
// ---------------------------------------------------------------------------
__global__ __launch_bounds__(256)
void z_gemm_kernel(const __hip_bfloat16* __restrict__ Sb,
                   const __hip_bfloat16* __restrict__ Ht,
                   float* __restrict__ Z,
                   const void* __restrict__ mask,
                   const float* __restrict__ rowsum,
                   int L_, int DH_, int T_)
{
    __shared__ __align__(16) __hip_bfloat16 lds_pool[24576];
    int bx, by, bz;
    xcd_swizzle(bx, by, bz);
    int* sh = (int*)lds_pool;
    const int w = detect_width_dev(mask, sh);
    const int cnt = count_valid_dev(mask, w, bz, L_, sh);
    const int Kdyn = (cnt + 127) & ~127;   // compact K
    __syncthreads();                       // sh reads done before pool reuse
    gemm_bt_body<float, 3, 64>(bx, by, bz, lds_pool,
        Sb, Ht, Z, Kdyn, L_, L_, DH_,
        (long)T_ * L_, (long)DH_ * L_, (long)T_ * DH_, 1.0f,
        (float*)rowsum, T_, 0);
}

// ---------------------------------------------------------------------------
extern "C" void kernel_launch(void* const* d_in, const int* in_sizes, int n_in,
                              void* d_out, int out_size, void* d_ws, size_t ws_size,
                              hipStream_t stream)
{
    constexpr int B = 4, L = 4096, DH = 1024, T = 1024, DG = 768, P = 256;

    const float* H  = (const float*)d_in[0];
    const float* G  = (const float*)d_in[1];
    const void*  mask = d_in[2];
    const float* Wk = (const float*)d_in[3];
    const float* Wq = (const float*)d_in[4];
    for (int i = 0; i < n_in; ++i) {
        switch (in_sizes[i]) {
            case B * L * DH: H    = (const float*)d_in[i]; break;
            case B * T * DG: G    = (const float*)d_in[i]; break;
            case B * L:      mask = d_in[i];               break;
            case P * DH:     Wk   = (const float*)d_in[i]; break;
            case P * DG:     Wq   = (const float*)d_in[i]; break;
        }
    }
    float* Z = (float*)d_out;

    char* ws = (char*)d_ws;
    __hip_bfloat16* Hbf  = (__hip_bfloat16*)ws;                      // [0, 32 MiB) — compact rows
    __hip_bfloat16* Ht   = (__hip_bfloat16*)(ws + (32l << 20));      // [32, 64) — compact cols
    __hip_bfloat16* Gbf  = (__hip_bfloat16*)(ws + (64l << 20));      // [64, 70)
    __hip_bfloat16* Qbf  = (__hip_bfloat16*)(ws + (70l << 20));      // [70, 72)
    __hip_bfloat16* Kbf  = (__hip_bfloat16*)(ws + (72l << 20));      // [72, 80) — compact rows
    __hip_bfloat16* Wkbf = (__hip_bfloat16*)(ws + (80l << 20));      // 512 KiB
    __hip_bfloat16* Wqbf = (__hip_bfloat16*)(ws + (80l << 20) + (512l << 10)); // 384 KiB
    float*          rowsum = (float*)(ws + (80l << 20) + (896l << 10));        // 16 KiB
    __hip_bfloat16* Sb   = (__hip_bfloat16*)(ws + (81l << 20));      // [81, 113) — compact cols

    const dim3 blk(256);

    // 1) fused prep: H gather/transpose w/ in-block scan (4096) +
    //    cvt Wk/Wq/G (3520) + rowsum zero (16)
    prep_all_kernel<<<dim3(7632), blk, 0, stream>>>(
        H, Hbf, Ht, mask,
        Wk, (unsigned short*)Wkbf, Wq, (unsigned short*)Wqbf,
        G, (unsigned short*)Gbf, rowsum, L, DH);

    // 2) Q = G @ Wq^T  and  K_c = Hbf_c @ Wk^T  in one launch
    qk_gemm_kernel<<<dim3(160, 2, 1), blk, 0, stream>>>(
        Gbf, Wqbf, Qbf, Hbf, Wkbf, Kbf, mask, DG, DH, P, L);

    // 3) P_c = exp(Q @ K_c^T / 16), cols >= Lc zeroed; rowsum atomics
    s_gemm_kernel<<<dim3(T / 128, L / 128, B), blk, 0, stream>>>(
        Qbf, Kbf, Sb, mask, rowsum, P, L, T);

    // 4) Z = (P_c @ Ht_c^T) / rowsum   64x128 tiles, full K, direct store
    z_gemm_kernel<<<dim3(T / 64, DH / 128, B), blk, 0, stream>>>(
        Sb, Ht, Z, mask, rowsum, L, DH, T);
}

// Round 9
// 217.212 us; speedup vs baseline: 1.6713x; 1.6713x over previous
//
#include <hip/hip_runtime.h>
#include <hip/hip_bf16.h>

// Problem: B=4, L=4096, DH=1024, T=1024, DG=768, P=256
// Inputs fp32 + bool mask (width auto-detect); OUTPUT fp32.
//
// MASK COMPACTION: ~50% of l are masked; masked columns have alpha == 0
// exactly. A single scan kernel (one block/batch) builds the valid-l list
// idx[b][c], Lc, Lc_pad ONCE; all passes work in compact index space.
// (Round-8 lesson: per-block recompute of the scan multiplied a 3us kernel
// into ~100us of redundant work — amortize, don't inline.)
//
// 5-DISPATCH PIPELINE:
//   1) scan:     width-detect + valid-l scan + rowsum zero (one block/batch)
//   2) prep_all: H gather/convert/transpose (reads idx) + cvt Wk/Wq/G
//   3) qk_gemm:  Q = Gbf@Wq^T and K_c = Hbf_c@Wk^T in one launch
//   4) s_gemm:   P_c = exp(Q@K_c^T/16), cols >= Lc zeroed by compare;
//                fp32 rowsum atomics
//   5) z_gemm:   Z = (P_c @ Ht_c^T) * (1/rowsum), M-SPLIT 64x128 tiles,
//                grid (16,8,4)=512 WGs, FULL compact K per WG -> normalized
//                direct fp32 store. No combine pass, no partial buffers.
//
// GEMM K-loop: COUNTED-VMCNT pipeline (T4), 3 LDS buffers, prefetch depth 2;
// GRANULE-XOR LDS swizzle (conflicts == 0, verified); bf16 epilogues via
// LDS-staged 16B/lane vectorized writeout; XCD-chunked blockIdx swizzle (T1).
// Body templated on BM (64 or 128): BM=64 waves cover 32x64, 3 gloads/tile
// (vmcnt(3)); BM=128 unchanged (vmcnt(4)).

typedef __attribute__((ext_vector_type(8))) short short8;   // 8 bf16 = 4 VGPRs
typedef __attribute__((ext_vector_type(4))) float f32x4;

static __device__ __forceinline__ unsigned short bf16bits(float x) {
    __hip_bfloat16 b = __float2bfloat16(x);
    return *(unsigned short*)&b;
}

// Async global->LDS, 16 B per lane. LDS dest = wave-uniform base + lane*16.
static __device__ __forceinline__ void gload_lds16(const __hip_bfloat16* g,
                                                   __hip_bfloat16* l)
{
    auto gp = (const __attribute__((address_space(1))) unsigned int*)(uintptr_t)g;
    auto lp = (__attribute__((address_space(3))) unsigned int*)(unsigned int)(uintptr_t)l;
    __builtin_amdgcn_global_load_lds(gp, lp, 16, 0, 0);
}

// ---------------------------------------------------------------------------
// Fused: mask width detect + valid-l compaction scan + rowsum zero.
// One block per batch (runs ONCE; consumers read the tiny outputs).
// ---------------------------------------------------------------------------
__global__ __launch_bounds__(256)
void scan_kernel(const void* __restrict__ mask,
                 unsigned short* __restrict__ idx,
                 int* __restrict__ lc, int* __restrict__ lcpad,
                 float* __restrict__ rowsum, int L, int T, int B)
{
    const int b = blockIdx.x;
    const int tid = threadIdx.x;

    // zero this batch's rowsum slice (S-pass accumulates atomically)
    for (int i = tid; i < T; i += 256) rowsum[(long)b * T + i] = 0.f;

    // --- width detection over the whole mask buffer (B*L bools) ---
    const unsigned char*  m8g  = (const unsigned char*)mask;
    const unsigned short* m16g = (const unsigned short*)mask;
    const unsigned int*   m32g = (const unsigned int*)mask;
    __shared__ int c1, c2, c4, c8, cp, wsh;
    if (tid == 0) { c1 = c2 = c4 = c8 = cp = 0; }
    __syncthreads();
    {
        const int N = B * L;   // 16384
        int l1 = 0, l2 = 0, l4 = 0, l8 = 0, lp = 0;
        for (int i = tid; i < N; i += 256) l1 += (m8g[i] != 0);
        for (int i = tid; i < N / 2; i += 256) {
            l2 += (m16g[i] != 0);
            lp += ((m8g[2 * i] != 0) == (m8g[2 * i + 1] != 0));
        }
        for (int i = tid; i < N / 4; i += 256) l4 += (m32g[i] != 0);
        for (int i = tid; i < N / 8; i += 256) l8 += ((m32g[2 * i] | m32g[2 * i + 1]) != 0);
        atomicAdd(&c1, l1); atomicAdd(&c2, l2); atomicAdd(&c4, l4);
        atomicAdd(&c8, l8); atomicAdd(&cp, lp);
    }
    __syncthreads();
    if (tid == 0) {
        const float f1 = fabsf(c1 / 16384.f - 0.5f);
        const float f2 = fabsf(c2 / 8192.f  - 0.5f);
        const float f4 = fabsf(c4 / 4096.f  - 0.5f);
        const float f8 = fabsf(c8 / 2048.f  - 0.5f);
        int w = 1; float best = f1;
        if (f2 < best) { best = f2; w = 2; }
        if (f4 < best) { best = f4; w = 4; }
        if (f8 < best) { best = f8; w = 8; }
        if (w == 1 && cp > 7400) w = 2;
        wsh = w;
    }
    __syncthreads();
    const int w = wsh;

    // --- compaction scan for batch b (16 l's per thread) ---
    const unsigned char*  m8  = (const unsigned char*)mask;
    const unsigned short* m16 = (const unsigned short*)mask;
    const unsigned int*   m32 = (const unsigned int*)mask;
    const uint2*          m64 = (const uint2*)mask;
    bool v[16];
    int cnt = 0;
    #pragma unroll
    for (int i = 0; i < 16; ++i) {
        const int l = tid * 16 + i;
        const long mi = (long)b * L + l;
        bool masked;
        if (w == 1)      masked = m8[mi] != 0;
        else if (w == 2) masked = m16[mi] != 0;
        else if (w == 4) masked = m32[mi] != 0;
        else             { uint2 q = m64[mi]; masked = (q.x | q.y) != 0; }
        v[i] = !masked;
        cnt += v[i] ? 1 : 0;
    }
    __shared__ int waveTot[4];
    int pre = cnt;
    #pragma unroll
    for (int off = 1; off < 64; off <<= 1) {
        const int t = __shfl_up(pre, off, 64);
        if ((tid & 63) >= off) pre += t;
    }
    if ((tid & 63) == 63) waveTot[tid >> 6] = pre;
    __syncthreads();
    int waveOff = 0;
    for (int wv = 0; wv < (tid >> 6); ++wv) waveOff += waveTot[wv];
    int o = waveOff + pre - cnt;          // exclusive prefix for this thread
    #pragma unroll
    for (int i = 0; i < 16; ++i)
        if (v[i]) idx[(long)b * L + (o++)] = (unsigned short)(tid * 16 + i);
    if (tid == 255) {
        const int total = waveOff + pre;
        lc[b] = total;
        lcpad[b] = (total + 127) & ~127;
    }
}

// ---------------------------------------------------------------------------
// Fused prep: blocks [0, 4096) = H gather/convert/transpose (64x64 tiles,
// reads the global idx buffer); blocks [4096, 7616) = cvt Wk/Wq/G.
// ---------------------------------------------------------------------------
__global__ __launch_bounds__(256)
void prep_all_kernel(const float* __restrict__ H,
                     __hip_bfloat16* __restrict__ Hbf,
                     __hip_bfloat16* __restrict__ Ht,
                     const unsigned short* __restrict__ idx,
                     const int* __restrict__ lc, const int* __restrict__ lcpad,
                     const float* __restrict__ Wk, unsigned short* __restrict__ Wkbf,
                     const float* __restrict__ Wq, unsigned short* __restrict__ Wqbf,
                     const float* __restrict__ G,  unsigned short* __restrict__ Gbf,
                     int L, int D)
{
    __shared__ __align__(16) __hip_bfloat16 tile[64][72];  // [d][c], pad 8
    int id = blockIdx.x;
    if (id < 4096) {
        // --- h gather: c-tile (id&63), d-tile ((id>>6)&15), b (id>>10) ---
        const int b  = id >> 10;
        const int c0 = (id & 63) * 64;
        if (c0 >= lcpad[b]) return;       // uniform: beyond padded extent
        const int d0 = ((id >> 6) & 15) * 64;
        const int Lcb = lc[b];
        const float* Hb = H + (long)b * L * D;
        __hip_bfloat16* Hbfb = Hbf + (long)b * L * D;
        __hip_bfloat16* Htb  = Ht  + (long)b * D * L;
        const int tx = threadIdx.x & 15, ty = threadIdx.x >> 4;  // 16 x 16
        #pragma unroll
        for (int p = 0; p < 4; ++p) {
            const int row = ty + p * 16;     // compact index within tile
            const int c = c0 + row;
            float4 v = {0.f, 0.f, 0.f, 0.f};
            if (c < Lcb) {
                const int l = idx[(long)b * L + c];
                v = *(const float4*)(&Hb[(long)l * D + d0 + tx * 4]);
            }
            ushort4 o;
            o.x = bf16bits(v.x); o.y = bf16bits(v.y);
            o.z = bf16bits(v.z); o.w = bf16bits(v.w);
            *(ushort4*)(&Hbfb[(long)c * D + d0 + tx * 4]) = o;
            tile[tx * 4 + 0][row] = __float2bfloat16(v.x);
            tile[tx * 4 + 1][row] = __float2bfloat16(v.y);
            tile[tx * 4 + 2][row] = __float2bfloat16(v.z);
            tile[tx * 4 + 3][row] = __float2bfloat16(v.w);
        }
        __syncthreads();
        const int ll = threadIdx.x & 7;      // 8 threads x 16B = 128B per d-row
        const int dq = threadIdx.x >> 3;     // 32 d-rows per pass
        #pragma unroll
        for (int q = 0; q < 2; ++q) {
            const int dd = dq + q * 32;
            const short8 v = *(const short8*)(&tile[dd][ll * 8]);
            *(short8*)(&Htb[(long)(d0 + dd) * L + c0 + ll * 8]) = v;
        }
        return;
    }
    // --- cvt ranges ---
    id -= 4096;
    const float* in; unsigned short* out; int n4;
    if (id < 256)       { in = Wk; out = Wkbf; n4 = (256 * 1024) / 4; }
    else if (id < 448)  { id -= 256; in = Wq; out = Wqbf; n4 = (256 * 768) / 4; }
    else                { id -= 448; in = G;  out = Gbf;  n4 = (4 * 1024 * 768) / 4; }
    const int i = id * 256 + threadIdx.x;
    if (i >= n4) return;
    float4 v = ((const float4*)in)[i];
    ushort4 o;
    o.x = bf16bits(v.x); o.y = bf16bits(v.y);
    o.z = bf16bits(v.z); o.w = bf16bits(v.w);
    ((ushort4*)out)[i] = o;
}

// ---------------------------------------------------------------------------
// GEMM body: C[M,N] (op)= scale * A[M,K] @ Bm[N,K]^T  (bf16 row-major)
// Tile BM x 128, 4 waves. BM=128: wave 64x64, 4x4 frags, 4 gloads/tile.
// BM=64: wave 32x64, 2x4 frags, 3 gloads/tile. Counted-vmcnt 3-buffer
// pipeline; lds_pool (48 KiB) reused for the bf16 epilogue.
// MODE 0: plain store (bf16 via LDS writeout / fp32 direct).
// MODE 2: P = exp(scale*acc); cols >= lcv -> 0; bf16 writeout; rowsum atomics.
// MODE 3: fp32 direct store * (1/rowsum[row])  (fused softmax normalize).
// ---------------------------------------------------------------------------
template <typename OutT, int MODE, int BM>
static __device__ __forceinline__
void gemm_bt_body(int bx, int by, int zb, __hip_bfloat16* lds_pool,
                  const __hip_bfloat16* __restrict__ A,
                  const __hip_bfloat16* __restrict__ Bm,
                  OutT* __restrict__ C,
                  int K, int lda, int ldb, int ldc,
                  long batchStrideA, long batchStrideB, long batchStrideC,
                  float scale,
                  float* __restrict__ rowsum, int rowsumStride, int lcv)
{
    constexpr int MI  = BM / 32;        // frag rows per wave
    constexpr int ACH = BM / 64;        // A staging chunks per wave
    constexpr int ATS = BM * 32;        // A tile elems per buffer

    A  += (long)zb * batchStrideA;
    Bm += (long)zb * batchStrideB;
    C  += (long)zb * batchStrideC;
    const int NT = K / 32;              // k-tiles (>= 4 always here)

    const int tid  = threadIdx.x;
    const int lane = tid & 63;
    const int wave = tid >> 6;
    const int wm = (wave & 1) * (BM / 2);
    const int wn = (wave >> 1) * 64;
    const int rowBase = bx * BM;
    const int colBase = by * 128;

    __hip_bfloat16* AsP = lds_pool;            // buf*ATS + row*32 + col
    __hip_bfloat16* BsP = lds_pool + 3 * ATS;

    f32x4 acc[MI][4];
    #pragma unroll
    for (int i = 0; i < MI; ++i)
        #pragma unroll
        for (int j = 0; j < 4; ++j)
            acc[i][j] = (f32x4){0.f, 0.f, 0.f, 0.f};

    // Staging: wave w covers BM/4 A-rows + 32 B-rows as 16-row x 1024 B chunks.
    // Lane i: LDS lands at (row = i>>2, granule g = i&3). Pre-swizzle the
    // GLOBAL source granule: q = g ^ ((row>>1)&3)  (involution per row).
    const int srow = lane >> 2;
    const int scol = ((lane & 3) ^ ((lane >> 3) & 3)) * 8;   // swizzled source col
    const long ar0 = (long)(rowBase + wave * (BM / 4) + srow) * lda;
    const long ar1 = ar0 + 16l * lda;                         // ACH==2 only
    const long br0 = (long)(colBase + wave * 32 + srow) * ldb;
    const long br1 = br0 + 16l * ldb;

    const int mrow = lane & 15;         // fragment m/n index
    // Swizzled fragment k-offset (row bases ≡0 mod 16 -> lane-only term).
    const int koff = (((lane >> 4) ^ ((lane >> 1) & 3)) * 8);

    // Per wave each tile issues EXACTLY ACH+2 global_load_lds ops.
    auto stage = [&](int buf, int t) {
        const int kk = t * 32 + scol;
        gload_lds16(A + ar0 + kk, AsP + buf * ATS + wave * (BM / 4) * 32);
        if constexpr (ACH == 2)
            gload_lds16(A + ar1 + kk, AsP + buf * ATS + wave * (BM / 4) * 32 + 512);
        gload_lds16(Bm + br0 + kk, BsP + buf * 4096 + wave * 1024);
        gload_lds16(Bm + br1 + kk, BsP + buf * 4096 + wave * 1024 + 512);
    };

    // Prologue: tiles 0,1 in flight. No barrier yet.
    stage(0, 0);
    stage(1, 1);

    int cur = 0;
    for (int t = 0; t < NT; ++t) {
        // Drain OWN tile-t loads only; tile t+1 stays in flight across the
        // barrier (counted vmcnt — never drain to 0 in the main loop).
        if (t + 1 < NT) {
            if constexpr (ACH == 2)
                asm volatile("s_waitcnt vmcnt(4)" ::: "memory");
            else
                asm volatile("s_waitcnt vmcnt(3)" ::: "memory");
        } else {
            asm volatile("s_waitcnt vmcnt(0)" ::: "memory");
        }
        __builtin_amdgcn_s_barrier();
        if (t + 2 < NT) {
            const int nxt2 = (cur >= 1) ? cur - 1 : cur + 2;   // (cur+2)%3
            stage(nxt2, t + 2);
        }

        short8 af[MI], bf[4];
        #pragma unroll
        for (int mi = 0; mi < MI; ++mi)
            af[mi] = *(const short8*)(AsP + cur * ATS + (wm + mi * 16 + mrow) * 32 + koff);
        #pragma unroll
        for (int ni = 0; ni < 4; ++ni)
            bf[ni] = *(const short8*)(BsP + cur * 4096 + (wn + ni * 16 + mrow) * 32 + koff);

        #pragma unroll
        for (int mi = 0; mi < MI; ++mi)
            #pragma unroll
            for (int ni = 0; ni < 4; ++ni)
                acc[mi][ni] = __builtin_amdgcn_mfma_f32_16x16x32_bf16(
                    af[mi], bf[ni], acc[mi][ni], 0, 0, 0);
        cur = (cur == 2) ? 0 : cur + 1;
    }

    // C/D layout (verified m89/m91): col = lane&15, row = (lane>>4)*4 + r
    const int crow0 = (lane >> 4) * 4;
    const int ccol  = lane & 15;

    if constexpr (MODE == 2) {
        // --- exp + compare-mask + rowsum; bf16 LDS-staged writeout ---
        __syncthreads();                   // pool safe: vmcnt(0) drained above
        __hip_bfloat16* cst = lds_pool;    // [128][136], granule^(row>>3)
        bool mk[4];
        #pragma unroll
        for (int ni = 0; ni < 4; ++ni)
            mk[ni] = (colBase + wn + ni * 16 + ccol) >= lcv;
        #pragma unroll
        for (int mi = 0; mi < MI; ++mi) {
            #pragma unroll
            for (int r = 0; r < 4; ++r) {
                const int row = wm + mi * 16 + crow0 + r;
                float rs = 0.f;
                #pragma unroll
                for (int ni = 0; ni < 4; ++ni) {
                    const int col = wn + ni * 16 + ccol;
                    const float e = mk[ni] ? 0.f
                                           : __expf(acc[mi][ni][r] * scale);
                    const __hip_bfloat16 pb = __float2bfloat16(e);
                    cst[row * 136 + (((col >> 3) ^ (row >> 3)) << 3) + (col & 7)] = pb;
                    rs += __bfloat162float(pb);
                }
                rs += __shfl_xor(rs, 1, 64);
                rs += __shfl_xor(rs, 2, 64);
                rs += __shfl_xor(rs, 4, 64);
                rs += __shfl_xor(rs, 8, 64);
                if ((lane & 15) == 0)
                    atomicAdd(&rowsum[(long)zb * rowsumStride + rowBase + row], rs);
            }
        }
        __syncthreads();
        const int g   = tid & 15;
        const int r4  = tid >> 4;
        const int lof = ((g ^ r4) << 3);
        #pragma unroll
        for (int k = 0; k < 8; ++k) {
            const int row = r4 * 8 + k;
            const short8 v = *(const short8*)(cst + row * 136 + lof);
            *(short8*)(&((__hip_bfloat16*)C)[(long)(rowBase + row) * ldc + colBase + g * 8]) = v;
        }
    } else if constexpr (MODE == 3) {
        // fp32 direct store with fused 1/rowsum normalize (Z output)
        #pragma unroll
        for (int mi = 0; mi < MI; ++mi) {
            #pragma unroll
            for (int r = 0; r < 4; ++r) {
                const int row = rowBase + wm + mi * 16 + crow0 + r;
                const float inv = 1.0f / rowsum[(long)zb * rowsumStride + row];
                #pragma unroll
                for (int ni = 0; ni < 4; ++ni) {
                    const int col = colBase + wn + ni * 16 + ccol;
                    ((float*)C)[(long)row * ldc + col] = acc[mi][ni][r] * inv;
                }
            }
        }
    } else if constexpr (sizeof(OutT) == 2) {
        // bf16 LDS-staged writeout (Q/K outputs)
        __syncthreads();
        __hip_bfloat16* cst = lds_pool;
        #pragma unroll
        for (int mi = 0; mi < MI; ++mi) {
            #pragma unroll
            for (int ni = 0; ni < 4; ++ni) {
                #pragma unroll
                for (int r = 0; r < 4; ++r) {
                    const int row = wm + mi * 16 + crow0 + r;
                    const int col = wn + ni * 16 + ccol;
                    cst[row * 136 + (((col >> 3) ^ (row >> 3)) << 3) + (col & 7)] =
                        __float2bfloat16(acc[mi][ni][r] * scale);
                }
            }
        }
        __syncthreads();
        const int g   = tid & 15;
        const int r4  = tid >> 4;
        const int lof = ((g ^ r4) << 3);
        #pragma unroll
        for (int k = 0; k < 8; ++k) {
            const int row = r4 * 8 + k;
            const short8 v = *(const short8*)(cst + row * 136 + lof);
            *(short8*)(&((__hip_bfloat16*)C)[(long)(rowBase + row) * ldc + colBase + g * 8]) = v;
        }
    } else {
        // fp32 direct stores
        #pragma unroll
        for (int mi = 0; mi < MI; ++mi) {
            #pragma unroll
            for (int ni = 0; ni < 4; ++ni) {
                #pragma unroll
                for (int r = 0; r < 4; ++r) {
                    const int row = rowBase + wm + mi * 16 + crow0 + r;
                    const int col = colBase + wn + ni * 16 + ccol;
                    ((float*)C)[(long)row * ldc + col] = acc[mi][ni][r] * scale;
                }
            }
        }
    }
}

// XCD-chunked swizzle (T1): remap so each XCD owns a contiguous grid chunk.
static __device__ __forceinline__ void xcd_swizzle(int& bx, int& by, int& bz)
{
    const int nwg = gridDim.x * gridDim.y * gridDim.z;
    bx = blockIdx.x; by = blockIdx.y; bz = blockIdx.z;
    if ((nwg & 7) == 0) {
        int lin = bx + gridDim.x * (by + gridDim.y * bz);
        lin = (lin & 7) * (nwg >> 3) + (lin >> 3);
        bx = lin % gridDim.x;
        const int t = lin / gridDim.x;
        by = t % gridDim.y;
        bz = t / gridDim.y;
    }
}

// ---------------------------------------------------------------------------
// Merged Q-GEMM + K-GEMM launch. Grid (160, 2, 1):
//   bx <  32: Q = Gbf @ Wq^T   [B*T=4096 rows, K=DG=768]
//   bx >= 32: K = Hbf_c @ Wk^T [B*L row cap, K=DH=1024]; lcpad row-exit
// ---------------------------------------------------------------------------
__global__ __launch_bounds__(256)
void qk_gemm_kernel(const __hip_bfloat16* __restrict__ Gbf,
                    const __hip_bfloat16* __restrict__ Wqbf,
                    __hip_bfloat16* __restrict__ Qbf,
                    const __hip_bfloat16* __restrict__ Hbf,
                    const __hip_bfloat16* __restrict__ Wkbf,
                    __hip_bfloat16* __restrict__ Kbf,
                    const int* __restrict__ lcpad,
                    int DG_, int DH_, int P_, int L_)
{
    __shared__ __align__(16) __hip_bfloat16 lds_pool[24576];
    int bx, by, bz;
    xcd_swizzle(bx, by, bz);
    if (bx < 32) {
        gemm_bt_body<__hip_bfloat16, 0, 128>(bx, by, 0, lds_pool,
            Gbf, Wqbf, Qbf, DG_, DG_, DG_, P_, 0, 0, 0, 1.0f,
            nullptr, 0, 0);
    } else {
        const int rowBase = (bx - 32) * 128;
        const int bb = rowBase / L_;
        if (rowBase - bb * L_ >= lcpad[bb]) return;
        gemm_bt_body<__hip_bfloat16, 0, 128>(bx - 32, by, 0, lds_pool,
            Hbf, Wkbf, Kbf, DH_, DH_, DH_, P_, 0, 0, 0, 1.0f,
            nullptr, 0, 0);
    }
}

// ---------------------------------------------------------------------------
// S-GEMM: P_c = exp(Q @ K_c^T * P^-0.5); cols >= Lc -> 0; rowsum atomics.
// ---------------------------------------------------------------------------
__global__ __launch_bounds__(256)
void s_gemm_kernel(const __hip_bfloat16* __restrict__ Qbf,
                   const __hip_bfloat16* __restrict__ Kbf,
                   __hip_bfloat16* __restrict__ Sb,
                   const int* __restrict__ lc, const int* __restrict__ lcpad,
                   float* __restrict__ rowsum,
                   int P_, int L_, int T_)
{
    __shared__ __align__(16) __hip_bfloat16 lds_pool[24576];
    int bx, by, bz;
    xcd_swizzle(bx, by, bz);
    if (by * 128 >= lcpad[bz]) return;   // masked-out col tile
    gemm_bt_body<__hip_bfloat16, 2, 128>(bx, by, bz, lds_pool,
        Qbf, Kbf, Sb, P_, P_, P_, L_,
        (long)T_ * P_, (long)L_ * P_, (long)T_ * L_, 0.0625f,
        rowsum, T_, lc[bz]);
}

// ---------------------------------------------------------------------------
// Z-GEMM: Z = (P_c @ Ht_c^T) * (1/rowsum). 64x128 tiles (M-split, full
// compact K per WG -> no combine pass), runtime K = Lc_pad.
// ---------------------------------------------------------------------------
__global__ __launch_bounds__(256)
void z_gemm_kernel(const __hip_bfloat16* __restrict__ Sb,
                   const __hip_bfloat16* __restrict__ Ht,
                   float* __restrict__ Z,
                   const int* __restrict__ lcpad,
                   const float* __restrict__ rowsum,
                   int L_, int DH_, int T_)
{
    __shared__ __align__(16) __hip_bfloat16 lds_pool[24576];
    int bx, by, bz;
    xcd_swizzle(bx, by, bz);
    gemm_bt_body<float, 3, 64>(bx, by, bz, lds_pool,
        Sb, Ht, Z, lcpad[bz], L_, L_, DH_,
        (long)T_ * L_, (long)DH_ * L_, (long)T_ * DH_, 1.0f,
        (float*)rowsum, T_, 0);
}

// ---------------------------------------------------------------------------
extern "C" void kernel_launch(void* const* d_in, const int* in_sizes, int n_in,
                              void* d_out, int out_size, void* d_ws, size_t ws_size,
                              hipStream_t stream)
{
    constexpr int B = 4, L = 4096, DH = 1024, T = 1024, DG = 768, P = 256;

    const float* H  = (const float*)d_in[0];
    const float* G  = (const float*)d_in[1];
    const void*  mask = d_in[2];
    const float* Wk = (const float*)d_in[3];
    const float* Wq = (const float*)d_in[4];
    for (int i = 0; i < n_in; ++i) {
        switch (in_sizes[i]) {
            case B * L * DH: H    = (const float*)d_in[i]; break;
            case B * T * DG: G    = (const float*)d_in[i]; break;
            case B * L:      mask = d_in[i];               break;
            case P * DH:     Wk   = (const float*)d_in[i]; break;
            case P * DG:     Wq   = (const float*)d_in[i]; break;
        }
    }
    float* Z = (float*)d_out;

    char* ws = (char*)d_ws;
    __hip_bfloat16* Hbf  = (__hip_bfloat16*)ws;                      // [0, 32 MiB) — compact rows
    __hip_bfloat16* Ht   = (__hip_bfloat16*)(ws + (32l << 20));      // [32, 64) — compact cols
    __hip_bfloat16* Gbf  = (__hip_bfloat16*)(ws + (64l << 20));      // [64, 70)
    __hip_bfloat16* Qbf  = (__hip_bfloat16*)(ws + (70l << 20));      // [70, 72)
    __hip_bfloat16* Kbf  = (__hip_bfloat16*)(ws + (72l << 20));      // [72, 80) — compact rows
    __hip_bfloat16* Wkbf = (__hip_bfloat16*)(ws + (80l << 20));      // 512 KiB
    __hip_bfloat16* Wqbf = (__hip_bfloat16*)(ws + (80l << 20) + (512l << 10)); // 384 KiB
    float*          rowsum    = (float*)(ws + (80l << 20) + (896l << 10));     // 16 KiB
    int*            lcBuf     = (int*)  (ws + (80l << 20) + (961l << 10));     // 16 B
    int*            lcpadBuf  = (int*)  (ws + (80l << 20) + (961l << 10) + 64);// 16 B
    unsigned short* idxBuf    = (unsigned short*)(ws + (80l << 20) + (962l << 10)); // 32 KiB
    __hip_bfloat16* Sb   = (__hip_bfloat16*)(ws + (81l << 20));      // [81, 113) — compact cols

    const dim3 blk(256);

    // 1) width + valid-l scan + rowsum zero (once; one block/batch)
    scan_kernel<<<dim3(B), blk, 0, stream>>>(
        mask, idxBuf, lcBuf, lcpadBuf, rowsum, L, T, B);

    // 2) fused prep: H gather/transpose (4096 blocks) + cvt Wk/Wq/G (3520)
    prep_all_kernel<<<dim3(7616), blk, 0, stream>>>(
        H, Hbf, Ht, idxBuf, lcBuf, lcpadBuf,
        Wk, (unsigned short*)Wkbf, Wq, (unsigned short*)Wqbf,
        G, (unsigned short*)Gbf, L, DH);

    // 3) Q = G @ Wq^T  and  K_c = Hbf_c @ Wk^T  in one launch
    qk_gemm_kernel<<<dim3(160, 2, 1), blk, 0, stream>>>(
        Gbf, Wqbf, Qbf, Hbf, Wkbf, Kbf, lcpadBuf, DG, DH, P, L);

    // 4) P_c = exp(Q @ K_c^T / 16), cols >= Lc zeroed; rowsum atomics
    s_gemm_kernel<<<dim3(T / 128, L / 128, B), blk, 0, stream>>>(
        Qbf, Kbf, Sb, lcBuf, lcpadBuf, rowsum, P, L, T);

    // 5) Z = (P_c @ Ht_c^T) / rowsum   64x128 tiles, full K, direct store
    z_gemm_kernel<<<dim3(T / 64, DH / 128, B), blk, 0, stream>>>(
        Sb, Ht, Z, lcpadBuf, rowsum, L, DH, T);
}